// Round 10
// baseline (91.381 us; speedup 1.0000x reference)
//
#include <hip/hip_runtime.h>
#include <math.h>

// Measured harness facts (R7/R8, absmax=0.0):
//   out_size = 2*B*F float32s; writable region = B*F complex64 (hc only);
//   F-1 pow2 (F=32769 @ B=256). Timed graph includes ~46us of harness
//   poison fills; kernel store floor = 67.1 MB / 6.3 TB/s ~= 11 us.
// R10 = R9 with fixes: __exp2f does not exist in HIP device code ->
// __builtin_amdgcn_exp2f; fast sin/cos via explicit revolution reduction
// (hw v_sin/v_cos domain ~±256 revs; worst phase ~257 revs).
// Masks/taper/rotation stay BIT-EXACT (ocml powf/sinf/cosf, rintf) so bin
// boundaries cannot flip; phase-path error ~1e-3 rad -> absmax ~1e-24.

#define F_MSUN   ((float)1.9884099021470415e30)
#define F_G      ((float)6.67430e-11)
#define F_PI     ((float)3.14159265358979323846)
#define F_C      ((float)299792458.0)
#define F_C3     ((float)(299792458.0*299792458.0*299792458.0))
#define F_PIG    ((float)(3.14159265358979323846*6.67430e-11))
#define F_5G     ((float)(5.0*6.67430e-11))
#define F_6_15   ((float)14.696938456699069)              /* 6.0**1.5 */
#define F_743    ((float)(743.0/252.0))
#define F_226    ((float)(226.0/15.0))
#define F_32PI5  ((float)(32.0*3.14159265358979323846/5.0))
#define F_BIG    ((float)(3058673.0/508032.0))
#define F_THIRD  ((float)(1.0/3.0))
#define F_56     ((float)(5.0/6.0))
#define F_M76    ((float)(-7.0/6.0))
#define F_M53    (-5.0f/3.0f)
#define F_INV2PI ((float)0.15915494309189535)

#define ROWS_PER_BLOCK 16
#define COLS_PER_THREAD 4
// per-row LDS record, 2 x float4:
//  q0: {Aprime = PIG*M/C3, Prow = 3/(128*eta), arow = p56*CdD*ci, fstart}
//  q1: {k0f, k1f, denf, pad}

__global__ __launch_bounds__(256) void cbc_kernel(
        const float* __restrict__ mass1,
        const float* __restrict__ mass2,
        const float* __restrict__ s1z,
        const float* __restrict__ s2z,
        const float* __restrict__ dist,
        const float* __restrict__ incl,
        float2* __restrict__ out,
        unsigned long long lim_f2,         // hard store bound (float2 units)
        int B, int F, float dff, float apsf) {
    __shared__ float4 srow[ROWS_PER_BLOCK * 2];

    int r0 = (int)blockIdx.y * ROWS_PER_BLOCK;

    if (threadIdx.x < ROWS_PER_BLOCK) {
        int r = r0 + (int)threadIdx.x;
        if (r < B) {
            // ---- bit-exact conditioning (identical to R7/R8, absmax 0.0) ----
            float m1 = mass1[r] * F_MSUN;
            float m2 = mass2[r] * F_MSUN;
            float s1 = s1z[r], s2 = s2z[r];
            float M  = m1 + m2;

            float fisco = F_C3 / (((F_G * M) * F_PI) * F_6_15);
            float f_min = fminf(fisco, 20.0f);

            float nu  = (m1 * m2) / (M * M);
            float as1 = fabsf(s1), as2 = fabsf(s2);
            float chi = (as1 > as2) ? as1 : as2;
            float c0  = ((5.0f * M) * F_G) / ((256.0f * nu) * F_C3);
            float cc2 = F_743 + ((11.0f * nu) / 3.0f);
            float cc3 = F_226 * chi - F_32PI5;
            float cc4 = (F_BIG + ((5429.0f * nu) / 504.0f)) + (((617.0f * nu) * nu) / 72.0f);
            float vv  = powf((F_PIG * M) * f_min, F_THIRD) / F_C;
            float x2 = vv * vv, x4 = x2 * x2, x8 = x4 * x4;
            float vm8 = 1.0f / x8;
            float poly = 1.0f + ((cc2 + ((cc3 + (cc4 * vv)) * vv)) * vv) * vv;
            float tchirp = (c0 * vm8) * poly;

            float c0b  = (F_5G * M) / ((256.0f * nu) * F_C3);
            float targ = 1.1f * tchirp;
            float fstart = (powf(c0b / targ, 0.375f) * F_C3) / (F_PIG * M);

            float eta = nu;
            float mc  = powf(eta, 0.6f) * M;
            float p56 = powf((F_G * mc) / F_C3, F_56);
            float CdD = F_C / dist[r];
            float ci  = cosf(incl[r]);

            float k0f = rintf(fstart / dff);               // bit-exact bins
            float k1f = rintf(f_min / dff);
            float denf = fmaxf(k1f - k0f, 1.0f);

            // hoisted per-row coefficients (divisions once per row)
            float Aprime = (F_PIG * M) / F_C3;
            float Prow   = 3.0f / (128.0f * eta);
            float arow   = (p56 * CdD) * ci;

            srow[(int)threadIdx.x * 2 + 0] = make_float4(Aprime, Prow, arow, fstart);
            srow[(int)threadIdx.x * 2 + 1] = make_float4(k0f, k1f, denf, 0.0f);
        }
    }
    __syncthreads();

    int kbase = (int)blockIdx.x * (256 * COLS_PER_THREAD) + (int)threadIdx.x;

    // per-column constants (bit-exact ocml; amortized over ROWS_PER_BLOCK rows)
    float fkj[COLS_PER_THREAD], ampc[COLS_PER_THREAD];
    float c2c[COLS_PER_THREAD], s2c[COLS_PER_THREAD];
    bool  live[COLS_PER_THREAD];
    #pragma unroll
    for (int j = 0; j < COLS_PER_THREAD; ++j) {
        int k = kbase + j * 256;
        float kf = (float)k;
        fkj[j]  = kf * dff;                 // exact (dff = 2^-5)
        live[j] = (k < F - 1);              // excludes nyquist and k >= F
        ampc[j] = powf(fkj[j], F_M76);      // inf at k=0; masked there
        float ang = apsf * kf;
        c2c[j] = cosf(ang); s2c[j] = sinf(ang);
    }

    int r1 = r0 + ROWS_PER_BLOCK; if (r1 > B) r1 = B;

    for (int r = r0; r < r1; ++r) {
        float4 q0 = srow[(r - r0) * 2 + 0];
        float4 q1 = srow[(r - r0) * 2 + 1];
        float Aprime = q0.x, Prow = q0.y, arow = q0.z, fstart = q0.w;
        float k0f = q1.x, k1f = q1.y, denf = q1.z;
        unsigned long long rowbase = (unsigned long long)r * (unsigned long long)F;

        #pragma unroll
        for (int j = 0; j < COLS_PER_THREAD; ++j) {
            int k = kbase + j * 256;
            if (k >= F) continue;
            float fk = fkj[j];
            bool on = live[j] && (fk >= fstart);

            float2 o = make_float2(0.0f, 0.0f);
            if (on) {
                // phase = (3/(128 eta)) * t^(-5/3), t = (PIG*M/C3)*fk
                float t  = Aprime * fk;
                float pw = __builtin_amdgcn_exp2f(__log2f(t) * F_M53);
                float phase = Prow * pw;
                // hw sin/cos take REVOLUTIONS, domain ~±256 revs; reduce.
                float ph_rev = phase * F_INV2PI;
                float fr = ph_rev - rintf(ph_rev);         // [-0.5, 0.5]
                float s = __builtin_amdgcn_sinf(fr);
                float c = __builtin_amdgcn_cosf(fr);
                float a2 = arow * ampc[j];
                float re = -(a2 * s);                      // -amp*ci*sin
                float im = -(a2 * c);                      // -amp*ci*cos
                float kf2 = (float)k;
                if (kf2 >= k0f && kf2 <= k1f) {            // taper (bit-exact)
                    float sc = 0.5f - 0.5f * cosf((F_PI * (kf2 - k0f)) / denf);
                    re *= sc; im *= sc;
                }
                o.x = re * c2c[j] - im * s2c[j];           // phase shift
                o.y = re * s2c[j] + im * c2c[j];
            }
            unsigned long long idx = rowbase + (unsigned long long)k;
            if (idx < lim_f2) out[idx] = o;                // fault-proof bound
        }
    }
}

extern "C" void kernel_launch(void* const* d_in, const int* in_sizes, int n_in,
                              void* d_out, int out_size, void* d_ws, size_t ws_size,
                              hipStream_t stream) {
    (void)d_ws; (void)ws_size;
    if (!d_in || !d_out || !in_sizes || n_in < 6 || out_size <= 0) return;
    const float* mass1 = (const float*)d_in[0];
    const float* mass2 = (const float*)d_in[1];
    const float* s1z   = (const float*)d_in[2];
    const float* s2z   = (const float*)d_in[3];
    const float* dist  = (const float*)d_in[4];
    const float* incl  = (const float*)d_in[5];
    if (!mass1 || !mass2 || !s1z || !s2z || !dist || !incl) return;
    long B = (long)in_sizes[0];
    if (B < 1 || B > (1L << 20)) return;

    // Measured: out_size = 2*B*F float32s (den=2 match); keep the general
    // scan for robustness (F-1 pow2 & F odd make candidates exclusive).
    auto ispow2 = [](long x) { return x > 0 && ((x & (x - 1)) == 0); };
    long F = 0; long matched_den = 0;
    const long dens[4] = {2, 4, 16, 8};
    for (int i = 0; i < 4 && F == 0; ++i) {
        long d = dens[i] * B;
        long cand = (long)out_size / d;
        if (cand > 1 && cand * d == (long)out_size && ispow2(cand - 1)) {
            F = cand; matched_den = dens[i];
        }
    }
    if (F == 0) return;

    // Minimal-allocation cap: byte-match -> out_size bytes, else out_size*4.
    unsigned long long cap_bytes = (unsigned long long)out_size
                                 * (matched_den == 16 ? 1ull : 4ull);
    unsigned long long lim_f2 = cap_bytes / 8ull;
    unsigned long long half = (unsigned long long)B * (unsigned long long)F;
    if (lim_f2 > half) lim_f2 = half;                      // hc only (measured)
    if (lim_f2 == 0) return;

    double df = 1024.0 / (double)(F - 1);
    float dff = (float)df;
    float apsf = (float)(2.0 * 3.14159265358979323846 * df * 0.5);

    dim3 grid((unsigned)((F + 256 * COLS_PER_THREAD - 1) / (256 * COLS_PER_THREAD)),
              (unsigned)((B + ROWS_PER_BLOCK - 1) / ROWS_PER_BLOCK));
    cbc_kernel<<<grid, dim3(256), 0, stream>>>(
        mass1, mass2, s1z, s2z, dist, incl,
        (float2*)d_out, lim_f2, (int)B, (int)F, dff, apsf);
}

// Round 11
// 89.189 us; speedup vs baseline: 1.0246x; 1.0246x over previous
//
#include <hip/hip_runtime.h>
#include <math.h>

// Measured harness facts:
//   out_size = 2*B*F float32s; writable d_out region = B*F complex64 (hc
//   only); F-1 pow2 (F=32769 @ B=256). Timed graph carries ~59us of fixed
//   harness reset nodes (268 MB d_ws poison fill ~45us + d_out poison +
//   input restores). R8->R10 showed kernel stuck ~31us across a 4x VALU
//   cut => grid-quantization bound (528 blocks = 2.06/CU, 45% tail).
// R11: two-kernel split. k1 -> row records into d_ws (bit-exact R10 math);
// k2 -> 4128 blocks (16/CU), no LDS/barrier, R10 fast-math unchanged.

#define F_MSUN   ((float)1.9884099021470415e30)
#define F_G      ((float)6.67430e-11)
#define F_PI     ((float)3.14159265358979323846)
#define F_C      ((float)299792458.0)
#define F_C3     ((float)(299792458.0*299792458.0*299792458.0))
#define F_PIG    ((float)(3.14159265358979323846*6.67430e-11))
#define F_5G     ((float)(5.0*6.67430e-11))
#define F_6_15   ((float)14.696938456699069)              /* 6.0**1.5 */
#define F_743    ((float)(743.0/252.0))
#define F_226    ((float)(226.0/15.0))
#define F_32PI5  ((float)(32.0*3.14159265358979323846/5.0))
#define F_BIG    ((float)(3058673.0/508032.0))
#define F_THIRD  ((float)(1.0/3.0))
#define F_56     ((float)(5.0/6.0))
#define F_M76    ((float)(-7.0/6.0))
#define F_M53    (-5.0f/3.0f)
#define F_INV2PI ((float)0.15915494309189535)

#define K2_ROWS 8   // rows per k2 block

// ---- shared row-record computation (bit-exact vs jax reference) ----
__device__ __forceinline__ void compute_row_rec(
        const float* mass1, const float* mass2, const float* s1z,
        const float* s2z, const float* dist, const float* incl,
        int r, float dff, float4& q0, float4& q1) {
    float m1 = mass1[r] * F_MSUN;
    float m2 = mass2[r] * F_MSUN;
    float s1 = s1z[r], s2 = s2z[r];
    float M  = m1 + m2;

    float fisco = F_C3 / (((F_G * M) * F_PI) * F_6_15);
    float f_min = fminf(fisco, 20.0f);

    float nu  = (m1 * m2) / (M * M);
    float as1 = fabsf(s1), as2 = fabsf(s2);
    float chi = (as1 > as2) ? as1 : as2;
    float c0  = ((5.0f * M) * F_G) / ((256.0f * nu) * F_C3);
    float cc2 = F_743 + ((11.0f * nu) / 3.0f);
    float cc3 = F_226 * chi - F_32PI5;
    float cc4 = (F_BIG + ((5429.0f * nu) / 504.0f)) + (((617.0f * nu) * nu) / 72.0f);
    float vv  = powf((F_PIG * M) * f_min, F_THIRD) / F_C;
    float x2 = vv * vv, x4 = x2 * x2, x8 = x4 * x4;
    float vm8 = 1.0f / x8;
    float poly = 1.0f + ((cc2 + ((cc3 + (cc4 * vv)) * vv)) * vv) * vv;
    float tchirp = (c0 * vm8) * poly;

    float c0b  = (F_5G * M) / ((256.0f * nu) * F_C3);
    float targ = 1.1f * tchirp;
    float fstart = (powf(c0b / targ, 0.375f) * F_C3) / (F_PIG * M);

    float eta = nu;
    float mc  = powf(eta, 0.6f) * M;
    float p56 = powf((F_G * mc) / F_C3, F_56);
    float CdD = F_C / dist[r];
    float ci  = cosf(incl[r]);

    float k0f = rintf(fstart / dff);               // bit-exact bins
    float k1f = rintf(f_min / dff);
    float denf = fmaxf(k1f - k0f, 1.0f);

    float Aprime = (F_PIG * M) / F_C3;
    float Prow   = 3.0f / (128.0f * eta);
    float arow   = (p56 * CdD) * ci;

    q0 = make_float4(Aprime, Prow, arow, fstart);
    q1 = make_float4(k0f, k1f, denf, 0.0f);
}

// ---- per-element fast path (identical to R10, absmax 0.0) ----
__device__ __forceinline__ float2 eval_elem(
        int k, bool live, float fk, float ampc, float c2c, float s2c,
        float4 q0, float4 q1) {
    float2 o = make_float2(0.0f, 0.0f);
    if (live && fk >= q0.w) {
        float t  = q0.x * fk;
        float pw = __builtin_amdgcn_exp2f(__log2f(t) * F_M53);
        float phase = q0.y * pw;
        float ph_rev = phase * F_INV2PI;
        float fr = ph_rev - rintf(ph_rev);         // [-0.5, 0.5] revolutions
        float s = __builtin_amdgcn_sinf(fr);
        float c = __builtin_amdgcn_cosf(fr);
        float a2 = q0.z * ampc;
        float re = -(a2 * s);
        float im = -(a2 * c);
        float kf = (float)k;
        if (kf >= q1.x && kf <= q1.y) {            // taper (bit-exact ocml)
            float sc = 0.5f - 0.5f * cosf((F_PI * (kf - q1.x)) / q1.z);
            re *= sc; im *= sc;
        }
        o.x = re * c2c - im * s2c;
        o.y = re * s2c + im * c2c;
    }
    return o;
}

__global__ void cbc_rows_kernel(
        const float* __restrict__ mass1, const float* __restrict__ mass2,
        const float* __restrict__ s1z,   const float* __restrict__ s2z,
        const float* __restrict__ dist,  const float* __restrict__ incl,
        float4* __restrict__ rc, int B, float dff) {
    int r = (int)blockIdx.x * (int)blockDim.x + (int)threadIdx.x;
    if (r >= B) return;
    float4 q0, q1;
    compute_row_rec(mass1, mass2, s1z, s2z, dist, incl, r, dff, q0, q1);
    rc[r * 2 + 0] = q0;
    rc[r * 2 + 1] = q1;
}

__global__ __launch_bounds__(256) void cbc_main_kernel(
        const float4* __restrict__ rc,
        float2* __restrict__ out,
        unsigned long long lim_f2, int B, int F, float dff, float apsf) {
    int k = (int)blockIdx.x * 256 + (int)threadIdx.x;
    if (k >= F) return;
    float kf = (float)k;
    float fk = kf * dff;                            // exact (dff = 2^-5)
    bool live = (k < F - 1);
    float ampc = powf(fk, F_M76);                   // bit-exact; inf@0 masked
    float ang = apsf * kf;
    float c2c = cosf(ang), s2c = sinf(ang);

    int r0 = (int)blockIdx.y * K2_ROWS;
    int r1 = r0 + K2_ROWS; if (r1 > B) r1 = B;

    for (int r = r0; r < r1; ++r) {
        float4 q0 = rc[r * 2 + 0];                  // wave-uniform, L1/L2-hot
        float4 q1 = rc[r * 2 + 1];
        float2 o = eval_elem(k, live, fk, ampc, c2c, s2c, q0, q1);
        unsigned long long idx = (unsigned long long)r * (unsigned long long)F
                               + (unsigned long long)k;
        if (idx < lim_f2) out[idx] = o;             // fault-proof bound
    }
}

// Fallback (no/insufficient d_ws): proven R10 single kernel.
#define FB_ROWS 16
#define FB_COLS 4
__global__ __launch_bounds__(256) void cbc_fallback_kernel(
        const float* __restrict__ mass1, const float* __restrict__ mass2,
        const float* __restrict__ s1z,   const float* __restrict__ s2z,
        const float* __restrict__ dist,  const float* __restrict__ incl,
        float2* __restrict__ out,
        unsigned long long lim_f2, int B, int F, float dff, float apsf) {
    __shared__ float4 srow[FB_ROWS * 2];
    int r0 = (int)blockIdx.y * FB_ROWS;
    if (threadIdx.x < FB_ROWS) {
        int r = r0 + (int)threadIdx.x;
        if (r < B) {
            float4 q0, q1;
            compute_row_rec(mass1, mass2, s1z, s2z, dist, incl, r, dff, q0, q1);
            srow[(int)threadIdx.x * 2 + 0] = q0;
            srow[(int)threadIdx.x * 2 + 1] = q1;
        }
    }
    __syncthreads();

    int kbase = (int)blockIdx.x * (256 * FB_COLS) + (int)threadIdx.x;
    float fkj[FB_COLS], ampc[FB_COLS], c2c[FB_COLS], s2c[FB_COLS];
    bool live[FB_COLS];
    #pragma unroll
    for (int j = 0; j < FB_COLS; ++j) {
        int k = kbase + j * 256;
        float kf = (float)k;
        fkj[j] = kf * dff;
        live[j] = (k < F - 1);
        ampc[j] = powf(fkj[j], F_M76);
        float ang = apsf * kf;
        c2c[j] = cosf(ang); s2c[j] = sinf(ang);
    }
    int r1 = r0 + FB_ROWS; if (r1 > B) r1 = B;
    for (int r = r0; r < r1; ++r) {
        float4 q0 = srow[(r - r0) * 2 + 0];
        float4 q1 = srow[(r - r0) * 2 + 1];
        unsigned long long rowbase = (unsigned long long)r * (unsigned long long)F;
        #pragma unroll
        for (int j = 0; j < FB_COLS; ++j) {
            int k = kbase + j * 256;
            if (k >= F) continue;
            float2 o = eval_elem(k, live[j], fkj[j], ampc[j], c2c[j], s2c[j], q0, q1);
            unsigned long long idx = rowbase + (unsigned long long)k;
            if (idx < lim_f2) out[idx] = o;
        }
    }
}

extern "C" void kernel_launch(void* const* d_in, const int* in_sizes, int n_in,
                              void* d_out, int out_size, void* d_ws, size_t ws_size,
                              hipStream_t stream) {
    if (!d_in || !d_out || !in_sizes || n_in < 6 || out_size <= 0) return;
    const float* mass1 = (const float*)d_in[0];
    const float* mass2 = (const float*)d_in[1];
    const float* s1z   = (const float*)d_in[2];
    const float* s2z   = (const float*)d_in[3];
    const float* dist  = (const float*)d_in[4];
    const float* incl  = (const float*)d_in[5];
    if (!mass1 || !mass2 || !s1z || !s2z || !dist || !incl) return;
    long B = (long)in_sizes[0];
    if (B < 1 || B > (1L << 20)) return;

    // F inference (measured: out_size = 2*B*F float32s; scan kept general).
    auto ispow2 = [](long x) { return x > 0 && ((x & (x - 1)) == 0); };
    long F = 0; long matched_den = 0;
    const long dens[4] = {2, 4, 16, 8};
    for (int i = 0; i < 4 && F == 0; ++i) {
        long d = dens[i] * B;
        long cand = (long)out_size / d;
        if (cand > 1 && cand * d == (long)out_size && ispow2(cand - 1)) {
            F = cand; matched_den = dens[i];
        }
    }
    if (F == 0) return;

    unsigned long long cap_bytes = (unsigned long long)out_size
                                 * (matched_den == 16 ? 1ull : 4ull);
    unsigned long long lim_f2 = cap_bytes / 8ull;
    unsigned long long half = (unsigned long long)B * (unsigned long long)F;
    if (lim_f2 > half) lim_f2 = half;               // hc only (measured)
    if (lim_f2 == 0) return;

    double df = 1024.0 / (double)(F - 1);
    float dff = (float)df;
    float apsf = (float)(2.0 * 3.14159265358979323846 * df * 0.5);

    size_t need_ws = (size_t)B * 32;                // 2 x float4 per row
    if (d_ws && ws_size >= need_ws) {
        float4* rc = (float4*)d_ws;
        cbc_rows_kernel<<<dim3((unsigned)((B + 255) / 256)), dim3(256), 0, stream>>>(
            mass1, mass2, s1z, s2z, dist, incl, rc, (int)B, dff);
        dim3 grid((unsigned)((F + 255) / 256),
                  (unsigned)((B + K2_ROWS - 1) / K2_ROWS));
        cbc_main_kernel<<<grid, dim3(256), 0, stream>>>(
            rc, (float2*)d_out, lim_f2, (int)B, (int)F, dff, apsf);
    } else {
        dim3 grid((unsigned)((F + 256 * FB_COLS - 1) / (256 * FB_COLS)),
                  (unsigned)((B + FB_ROWS - 1) / FB_ROWS));
        cbc_fallback_kernel<<<grid, dim3(256), 0, stream>>>(
            mass1, mass2, s1z, s2z, dist, incl,
            (float2*)d_out, lim_f2, (int)B, (int)F, dff, apsf);
    }
}

// Round 12
// 88.168 us; speedup vs baseline: 1.0364x; 1.0116x over previous
//
#include <hip/hip_runtime.h>
#include <math.h>

// Measured: out_size = 2*B*F float32s; writable d_out = B*F complex64 (hc
// only); F-1 pow2 (F=32769 @ B=256). Fixed graph cost ~57us of poison
// fills (268MB d_ws @45us + 67MB d_out @11us) at 5.9 TB/s. Kernel pinned
// ~30us across R8/R10/R11 (VALU cut, grid x8 both neutral) => store-pattern
// bound: row-strided 2KB chunks (stride 256KB+8) reach only 2.2 TB/s.
// R12: flat LINEAR store stream (identical shape to the 5.9 TB/s fill).

#define F_MSUN   ((float)1.9884099021470415e30)
#define F_G      ((float)6.67430e-11)
#define F_PI     ((float)3.14159265358979323846)
#define F_C      ((float)299792458.0)
#define F_C3     ((float)(299792458.0*299792458.0*299792458.0))
#define F_PIG    ((float)(3.14159265358979323846*6.67430e-11))
#define F_5G     ((float)(5.0*6.67430e-11))
#define F_6_15   ((float)14.696938456699069)              /* 6.0**1.5 */
#define F_743    ((float)(743.0/252.0))
#define F_226    ((float)(226.0/15.0))
#define F_32PI5  ((float)(32.0*3.14159265358979323846/5.0))
#define F_BIG    ((float)(3058673.0/508032.0))
#define F_THIRD  ((float)(1.0/3.0))
#define F_56     ((float)(5.0/6.0))
#define F_M76    ((float)(-7.0/6.0))
#define F_M53    (-5.0f/3.0f)
#define F_INV2PI ((float)0.15915494309189535)

// ---- row-record computation (bit-exact vs jax reference) ----
__device__ __forceinline__ void compute_row_rec(
        const float* mass1, const float* mass2, const float* s1z,
        const float* s2z, const float* dist, const float* incl,
        int r, float dff, float4& q0, float4& q1) {
    float m1 = mass1[r] * F_MSUN;
    float m2 = mass2[r] * F_MSUN;
    float s1 = s1z[r], s2 = s2z[r];
    float M  = m1 + m2;

    float fisco = F_C3 / (((F_G * M) * F_PI) * F_6_15);
    float f_min = fminf(fisco, 20.0f);

    float nu  = (m1 * m2) / (M * M);
    float as1 = fabsf(s1), as2 = fabsf(s2);
    float chi = (as1 > as2) ? as1 : as2;
    float c0  = ((5.0f * M) * F_G) / ((256.0f * nu) * F_C3);
    float cc2 = F_743 + ((11.0f * nu) / 3.0f);
    float cc3 = F_226 * chi - F_32PI5;
    float cc4 = (F_BIG + ((5429.0f * nu) / 504.0f)) + (((617.0f * nu) * nu) / 72.0f);
    float vv  = powf((F_PIG * M) * f_min, F_THIRD) / F_C;
    float x2 = vv * vv, x4 = x2 * x2, x8 = x4 * x4;
    float vm8 = 1.0f / x8;
    float poly = 1.0f + ((cc2 + ((cc3 + (cc4 * vv)) * vv)) * vv) * vv;
    float tchirp = (c0 * vm8) * poly;

    float c0b  = (F_5G * M) / ((256.0f * nu) * F_C3);
    float targ = 1.1f * tchirp;
    float fstart = (powf(c0b / targ, 0.375f) * F_C3) / (F_PIG * M);

    float eta = nu;
    float mc  = powf(eta, 0.6f) * M;
    float p56 = powf((F_G * mc) / F_C3, F_56);
    float CdD = F_C / dist[r];
    float ci  = cosf(incl[r]);

    float k0f = rintf(fstart / dff);               // bit-exact bins
    float k1f = rintf(f_min / dff);
    float denf = fmaxf(k1f - k0f, 1.0f);

    float Aprime = (F_PIG * M) / F_C3;
    float Prow   = 3.0f / (128.0f * eta);
    float arow   = (p56 * CdD) * ci;

    q0 = make_float4(Aprime, Prow, arow, fstart);
    q1 = make_float4(k0f, k1f, denf, 0.0f);
}

__global__ void cbc_rows_kernel(
        const float* __restrict__ mass1, const float* __restrict__ mass2,
        const float* __restrict__ s1z,   const float* __restrict__ s2z,
        const float* __restrict__ dist,  const float* __restrict__ incl,
        float4* __restrict__ rc, int B, float dff) {
    int r = (int)blockIdx.x * (int)blockDim.x + (int)threadIdx.x;
    if (r >= B) return;
    float4 q0, q1;
    compute_row_rec(mass1, mass2, s1z, s2z, dist, incl, r, dff, q0, q1);
    rc[r * 2 + 0] = q0;
    rc[r * 2 + 1] = q1;
}

// ---- per-element fast evaluation (R10-proven phase path) ----
__device__ __forceinline__ float2 eval_flat(
        unsigned int k, int F, float dff, float hdff, float4 q0, float4 q1) {
    float2 o = make_float2(0.0f, 0.0f);
    float kf = (float)k;
    float fk = kf * dff;                           // exact (dff pow2)
    if ((int)k != F - 1 && fk >= q0.w) {
        float t  = q0.x * fk;
        float pw = __builtin_amdgcn_exp2f(__log2f(t) * F_M53);
        float phase = q0.y * pw;
        float ph_rev = phase * F_INV2PI;
        float fr = ph_rev - rintf(ph_rev);         // [-0.5,0.5] revolutions
        float s = __builtin_amdgcn_sinf(fr);
        float c = __builtin_amdgcn_cosf(fr);
        float ampc = __builtin_amdgcn_exp2f(__log2f(fk) * F_M76);
        float a2 = q0.z * ampc;
        float re = -(a2 * s);
        float im = -(a2 * c);
        if (kf >= q1.x && kf <= q1.y) {            // taper (rare; ocml cos)
            float sc = 0.5f - 0.5f * cosf((F_PI * (kf - q1.x)) / q1.z);
            re *= sc; im *= sc;
        }
        // phase shift: rev = kf*(0.5*dff) is EXACT (pow2 scale);
        // fr2 = frac -> hw sin/cos in range.
        float rev = kf * hdff;
        float fr2 = rev - rintf(rev);
        float c2c = __builtin_amdgcn_cosf(fr2);
        float s2c = __builtin_amdgcn_sinf(fr2);
        o.x = re * c2c - im * s2c;
        o.y = re * s2c + im * c2c;
    }
    return o;
}

#define EPT 8   // float2 elements per thread; block = 2048 contiguous elems
__global__ __launch_bounds__(256) void cbc_flat_main(
        const float4* __restrict__ rc,
        float2* __restrict__ out,
        unsigned int total, int F, float dff, float hdff) {
    unsigned int e0 = blockIdx.x * (256u * EPT) + threadIdx.x;
    if (e0 >= total) return;
    unsigned int r = e0 / (unsigned int)F;         // one div per thread
    unsigned int k = e0 - r * (unsigned int)F;

    #pragma unroll
    for (int j = 0; j < EPT; ++j) {
        unsigned int e = e0 + (unsigned int)j * 256u;
        if (j > 0) {
            k += 256u;                             // needs F > 2048 (guarded)
            if (k >= (unsigned int)F) { k -= (unsigned int)F; r += 1u; }
        }
        if (e >= total) break;
        float4 q0 = rc[r * 2 + 0];                 // L1/L2-hot, ~wave-uniform
        float4 q1 = rc[r * 2 + 1];
        out[e] = eval_flat(k, F, dff, hdff, q0, q1);  // linear store stream
    }
}

// Fallback (no d_ws / small F / huge sizes): proven R10 single kernel.
#define FB_ROWS 16
#define FB_COLS 4
__global__ __launch_bounds__(256) void cbc_fallback_kernel(
        const float* __restrict__ mass1, const float* __restrict__ mass2,
        const float* __restrict__ s1z,   const float* __restrict__ s2z,
        const float* __restrict__ dist,  const float* __restrict__ incl,
        float2* __restrict__ out,
        unsigned long long lim_f2, int B, int F, float dff, float apsf) {
    __shared__ float4 srow[FB_ROWS * 2];
    int r0 = (int)blockIdx.y * FB_ROWS;
    if (threadIdx.x < FB_ROWS) {
        int r = r0 + (int)threadIdx.x;
        if (r < B) {
            float4 q0, q1;
            compute_row_rec(mass1, mass2, s1z, s2z, dist, incl, r, dff, q0, q1);
            srow[(int)threadIdx.x * 2 + 0] = q0;
            srow[(int)threadIdx.x * 2 + 1] = q1;
        }
    }
    __syncthreads();

    int kbase = (int)blockIdx.x * (256 * FB_COLS) + (int)threadIdx.x;
    int r1 = r0 + FB_ROWS; if (r1 > B) r1 = B;
    for (int r = r0; r < r1; ++r) {
        float4 q0 = srow[(r - r0) * 2 + 0];
        float4 q1 = srow[(r - r0) * 2 + 1];
        unsigned long long rowbase = (unsigned long long)r * (unsigned long long)F;
        #pragma unroll
        for (int j = 0; j < FB_COLS; ++j) {
            int k = kbase + j * 256;
            if (k >= F) continue;
            float hdff = 0.0f; // unused path variant below
            (void)hdff;
            // reuse eval_flat (rotation reduction valid for any pow2 dff)
            float2 o = eval_flat((unsigned int)k, F, dff, 0.5f * dff, q0, q1);
            unsigned long long idx = rowbase + (unsigned long long)k;
            if (idx < lim_f2) out[idx] = o;
        }
    }
}

extern "C" void kernel_launch(void* const* d_in, const int* in_sizes, int n_in,
                              void* d_out, int out_size, void* d_ws, size_t ws_size,
                              hipStream_t stream) {
    if (!d_in || !d_out || !in_sizes || n_in < 6 || out_size <= 0) return;
    const float* mass1 = (const float*)d_in[0];
    const float* mass2 = (const float*)d_in[1];
    const float* s1z   = (const float*)d_in[2];
    const float* s2z   = (const float*)d_in[3];
    const float* dist  = (const float*)d_in[4];
    const float* incl  = (const float*)d_in[5];
    if (!mass1 || !mass2 || !s1z || !s2z || !dist || !incl) return;
    long B = (long)in_sizes[0];
    if (B < 1 || B > (1L << 20)) return;

    // F inference (measured: out_size = 2*B*F float32s; scan kept general).
    auto ispow2 = [](long x) { return x > 0 && ((x & (x - 1)) == 0); };
    long F = 0; long matched_den = 0;
    const long dens[4] = {2, 4, 16, 8};
    for (int i = 0; i < 4 && F == 0; ++i) {
        long d = dens[i] * B;
        long cand = (long)out_size / d;
        if (cand > 1 && cand * d == (long)out_size && ispow2(cand - 1)) {
            F = cand; matched_den = dens[i];
        }
    }
    if (F == 0) return;

    unsigned long long cap_bytes = (unsigned long long)out_size
                                 * (matched_den == 16 ? 1ull : 4ull);
    unsigned long long lim_f2 = cap_bytes / 8ull;
    unsigned long long half = (unsigned long long)B * (unsigned long long)F;
    if (lim_f2 > half) lim_f2 = half;               // hc only (measured)
    if (lim_f2 == 0) return;

    double df = 1024.0 / (double)(F - 1);
    float dff = (float)df;
    float hdff = 0.5f * dff;                        // pow2: rev scale, exact
    float apsf = (float)(2.0 * 3.14159265358979323846 * df * 0.5);

    size_t need_ws = (size_t)B * 32;                // 2 x float4 per row
    bool flat_ok = d_ws && ws_size >= need_ws && F > 2048 &&
                   lim_f2 == half && half < (1ull << 31);
    if (flat_ok) {
        float4* rc = (float4*)d_ws;
        cbc_rows_kernel<<<dim3((unsigned)((B + 255) / 256)), dim3(256), 0, stream>>>(
            mass1, mass2, s1z, s2z, dist, incl, rc, (int)B, dff);
        unsigned int total = (unsigned int)half;
        unsigned int nblk = (total + 2048u - 1u) / 2048u;
        cbc_flat_main<<<dim3(nblk), dim3(256), 0, stream>>>(
            rc, (float2*)d_out, total, (int)F, dff, hdff);
    } else {
        dim3 grid((unsigned)((F + 256 * FB_COLS - 1) / (256 * FB_COLS)),
                  (unsigned)((B + FB_ROWS - 1) / FB_ROWS));
        cbc_fallback_kernel<<<grid, dim3(256), 0, stream>>>(
            mass1, mass2, s1z, s2z, dist, incl,
            (float2*)d_out, lim_f2, (int)B, (int)F, dff, apsf);
    }
}

// Round 14
// 87.994 us; speedup vs baseline: 1.0385x; 1.0020x over previous
//
#include <hip/hip_runtime.h>
#include <math.h>

// Measured: out_size = 2*B*F float32s; writable d_out = B*F complex64 (hc
// only); F-1 pow2 (F=32769 @ B=256). Fixed graph cost 58.9us (poison
// fills at 5.9 TB/s). Kernel pinned ~29-31us across R8-R12 (VALU cut,
// grid x8, linear stream all ~neutral) = 2.3 TB/s effective stores.
// R14 = R13 with fix: __builtin_nontemporal_store needs a NATIVE vector
// type (clang ext_vector_type), not HIP's float4 class.

#define F_MSUN   ((float)1.9884099021470415e30)
#define F_G      ((float)6.67430e-11)
#define F_PI     ((float)3.14159265358979323846)
#define F_C      ((float)299792458.0)
#define F_C3     ((float)(299792458.0*299792458.0*299792458.0))
#define F_PIG    ((float)(3.14159265358979323846*6.67430e-11))
#define F_5G     ((float)(5.0*6.67430e-11))
#define F_6_15   ((float)14.696938456699069)              /* 6.0**1.5 */
#define F_743    ((float)(743.0/252.0))
#define F_226    ((float)(226.0/15.0))
#define F_32PI5  ((float)(32.0*3.14159265358979323846/5.0))
#define F_BIG    ((float)(3058673.0/508032.0))
#define F_THIRD  ((float)(1.0/3.0))
#define F_56     ((float)(5.0/6.0))
#define F_M76    ((float)(-7.0/6.0))
#define F_M53    (-5.0f/3.0f)
#define F_INV2PI ((float)0.15915494309189535)

typedef float nv4 __attribute__((ext_vector_type(4)));   // native vec for NT store

// ---- row-record computation (bit-exact vs jax reference) ----
__device__ __forceinline__ void compute_row_rec(
        const float* mass1, const float* mass2, const float* s1z,
        const float* s2z, const float* dist, const float* incl,
        int r, float dff, float4& q0, float4& q1) {
    float m1 = mass1[r] * F_MSUN;
    float m2 = mass2[r] * F_MSUN;
    float s1 = s1z[r], s2 = s2z[r];
    float M  = m1 + m2;

    float fisco = F_C3 / (((F_G * M) * F_PI) * F_6_15);
    float f_min = fminf(fisco, 20.0f);

    float nu  = (m1 * m2) / (M * M);
    float as1 = fabsf(s1), as2 = fabsf(s2);
    float chi = (as1 > as2) ? as1 : as2;
    float c0  = ((5.0f * M) * F_G) / ((256.0f * nu) * F_C3);
    float cc2 = F_743 + ((11.0f * nu) / 3.0f);
    float cc3 = F_226 * chi - F_32PI5;
    float cc4 = (F_BIG + ((5429.0f * nu) / 504.0f)) + (((617.0f * nu) * nu) / 72.0f);
    float vv  = powf((F_PIG * M) * f_min, F_THIRD) / F_C;
    float x2 = vv * vv, x4 = x2 * x2, x8 = x4 * x4;
    float vm8 = 1.0f / x8;
    float poly = 1.0f + ((cc2 + ((cc3 + (cc4 * vv)) * vv)) * vv) * vv;
    float tchirp = (c0 * vm8) * poly;

    float c0b  = (F_5G * M) / ((256.0f * nu) * F_C3);
    float targ = 1.1f * tchirp;
    float fstart = (powf(c0b / targ, 0.375f) * F_C3) / (F_PIG * M);

    float eta = nu;
    float mc  = powf(eta, 0.6f) * M;
    float p56 = powf((F_G * mc) / F_C3, F_56);
    float CdD = F_C / dist[r];
    float ci  = cosf(incl[r]);

    float k0f = rintf(fstart / dff);               // bit-exact bins
    float k1f = rintf(f_min / dff);
    float denf = fmaxf(k1f - k0f, 1.0f);

    float Aprime = (F_PIG * M) / F_C3;
    float Prow   = 3.0f / (128.0f * eta);
    float arow   = (p56 * CdD) * ci;

    q0 = make_float4(Aprime, Prow, arow, fstart);
    q1 = make_float4(k0f, k1f, denf, 0.0f);
}

__global__ void cbc_rows_kernel(
        const float* __restrict__ mass1, const float* __restrict__ mass2,
        const float* __restrict__ s1z,   const float* __restrict__ s2z,
        const float* __restrict__ dist,  const float* __restrict__ incl,
        float4* __restrict__ rc, int B, float dff) {
    int r = (int)blockIdx.x * (int)blockDim.x + (int)threadIdx.x;
    if (r >= B) return;
    float4 q0, q1;
    compute_row_rec(mass1, mass2, s1z, s2z, dist, incl, r, dff, q0, q1);
    rc[r * 2 + 0] = q0;
    rc[r * 2 + 1] = q1;
}

// ---- per-element fast evaluation (R10/R12-proven, absmax 0.0) ----
__device__ __forceinline__ float2 eval_flat(
        unsigned int k, int F, float dff, float hdff, float4 q0, float4 q1) {
    float2 o = make_float2(0.0f, 0.0f);
    float kf = (float)k;
    float fk = kf * dff;                           // exact (dff pow2)
    if ((int)k != F - 1 && fk >= q0.w) {
        float t  = q0.x * fk;
        float pw = __builtin_amdgcn_exp2f(__log2f(t) * F_M53);
        float phase = q0.y * pw;
        float ph_rev = phase * F_INV2PI;
        float fr = ph_rev - rintf(ph_rev);         // [-0.5,0.5] revolutions
        float s = __builtin_amdgcn_sinf(fr);
        float c = __builtin_amdgcn_cosf(fr);
        float ampc = __builtin_amdgcn_exp2f(__log2f(fk) * F_M76);
        float a2 = q0.z * ampc;
        float re = -(a2 * s);
        float im = -(a2 * c);
        if (kf >= q1.x && kf <= q1.y) {            // taper (rare; ocml cos)
            float sc = 0.5f - 0.5f * cosf((F_PI * (kf - q1.x)) / q1.z);
            re *= sc; im *= sc;
        }
        float rev = kf * hdff;                     // exact pow2 scale
        float fr2 = rev - rintf(rev);
        float c2c = __builtin_amdgcn_cosf(fr2);
        float s2c = __builtin_amdgcn_sinf(fr2);
        o.x = re * c2c - im * s2c;
        o.y = re * s2c + im * c2c;
    }
    return o;
}

// Block owns 2048 contiguous elements (needs F > 2048 -> spans <= 2 rows).
// 4 passes x (256 threads x 2 elems) -> one nv4 nontemporal store each.
#define PASSES 4
__global__ __launch_bounds__(256) void cbc_flat2_main(
        const float4* __restrict__ rc,
        nv4* __restrict__ out4,
        unsigned int totalPairs, int F, int B, float dff, float hdff) {
    unsigned int blockBase = blockIdx.x * 2048u;           // element index
    unsigned int rA = blockBase / (unsigned int)F;         // one div/block
    if (rA >= (unsigned int)B) return;
    unsigned int kA = blockBase - rA * (unsigned int)F;
    unsigned int rB = rA + 1u;
    if (rB >= (unsigned int)B) rB = (unsigned int)B - 1u;

    // both candidate row records in registers (no per-pass reloads)
    float4 qA0 = rc[rA * 2 + 0], qA1 = rc[rA * 2 + 1];
    float4 qB0 = rc[rB * 2 + 0], qB1 = rc[rB * 2 + 1];

    #pragma unroll
    for (int p = 0; p < PASSES; ++p) {
        unsigned int o = (unsigned int)p * 512u + threadIdx.x * 2u;
        unsigned int pairIdx = (blockBase + o) >> 1;
        if (pairIdx >= totalPairs) break;
        float2 e0, e1;
        {
            unsigned int k = kA + o;
            bool wrap = (k >= (unsigned int)F);
            unsigned int kk = wrap ? (k - (unsigned int)F) : k;
            float4 q0 = wrap ? qB0 : qA0;
            float4 q1 = wrap ? qB1 : qA1;
            e0 = eval_flat(kk, F, dff, hdff, q0, q1);
        }
        {
            unsigned int k = kA + o + 1u;
            bool wrap = (k >= (unsigned int)F);
            unsigned int kk = wrap ? (k - (unsigned int)F) : k;
            float4 q0 = wrap ? qB0 : qA0;
            float4 q1 = wrap ? qB1 : qA1;
            e1 = eval_flat(kk, F, dff, hdff, q0, q1);
        }
        nv4 v; v.x = e0.x; v.y = e0.y; v.z = e1.x; v.w = e1.y;
        __builtin_nontemporal_store(v, out4 + pairIdx);    // 16B/lane, linear
    }
}

// Fallback (no d_ws / small F / odd sizes): proven R10-style single kernel.
#define FB_ROWS 16
#define FB_COLS 4
__global__ __launch_bounds__(256) void cbc_fallback_kernel(
        const float* __restrict__ mass1, const float* __restrict__ mass2,
        const float* __restrict__ s1z,   const float* __restrict__ s2z,
        const float* __restrict__ dist,  const float* __restrict__ incl,
        float2* __restrict__ out,
        unsigned long long lim_f2, int B, int F, float dff, float apsf) {
    __shared__ float4 srow[FB_ROWS * 2];
    int r0 = (int)blockIdx.y * FB_ROWS;
    if (threadIdx.x < FB_ROWS) {
        int r = r0 + (int)threadIdx.x;
        if (r < B) {
            float4 q0, q1;
            compute_row_rec(mass1, mass2, s1z, s2z, dist, incl, r, dff, q0, q1);
            srow[(int)threadIdx.x * 2 + 0] = q0;
            srow[(int)threadIdx.x * 2 + 1] = q1;
        }
    }
    __syncthreads();

    int kbase = (int)blockIdx.x * (256 * FB_COLS) + (int)threadIdx.x;
    int r1 = r0 + FB_ROWS; if (r1 > B) r1 = B;
    for (int r = r0; r < r1; ++r) {
        float4 q0 = srow[(r - r0) * 2 + 0];
        float4 q1 = srow[(r - r0) * 2 + 1];
        unsigned long long rowbase = (unsigned long long)r * (unsigned long long)F;
        #pragma unroll
        for (int j = 0; j < FB_COLS; ++j) {
            int k = kbase + j * 256;
            if (k >= F) continue;
            float2 o = eval_flat((unsigned int)k, F, dff, 0.5f * dff, q0, q1);
            unsigned long long idx = rowbase + (unsigned long long)k;
            if (idx < lim_f2) out[idx] = o;
        }
    }
}

extern "C" void kernel_launch(void* const* d_in, const int* in_sizes, int n_in,
                              void* d_out, int out_size, void* d_ws, size_t ws_size,
                              hipStream_t stream) {
    if (!d_in || !d_out || !in_sizes || n_in < 6 || out_size <= 0) return;
    const float* mass1 = (const float*)d_in[0];
    const float* mass2 = (const float*)d_in[1];
    const float* s1z   = (const float*)d_in[2];
    const float* s2z   = (const float*)d_in[3];
    const float* dist  = (const float*)d_in[4];
    const float* incl  = (const float*)d_in[5];
    if (!mass1 || !mass2 || !s1z || !s2z || !dist || !incl) return;
    long B = (long)in_sizes[0];
    if (B < 1 || B > (1L << 20)) return;

    // F inference (measured: out_size = 2*B*F float32s; scan kept general).
    auto ispow2 = [](long x) { return x > 0 && ((x & (x - 1)) == 0); };
    long F = 0; long matched_den = 0;
    const long dens[4] = {2, 4, 16, 8};
    for (int i = 0; i < 4 && F == 0; ++i) {
        long d = dens[i] * B;
        long cand = (long)out_size / d;
        if (cand > 1 && cand * d == (long)out_size && ispow2(cand - 1)) {
            F = cand; matched_den = dens[i];
        }
    }
    if (F == 0) return;

    unsigned long long cap_bytes = (unsigned long long)out_size
                                 * (matched_den == 16 ? 1ull : 4ull);
    unsigned long long lim_f2 = cap_bytes / 8ull;
    unsigned long long half = (unsigned long long)B * (unsigned long long)F;
    if (lim_f2 > half) lim_f2 = half;               // hc only (measured)
    if (lim_f2 == 0) return;

    double df = 1024.0 / (double)(F - 1);
    float dff = (float)df;
    float hdff = 0.5f * dff;                        // pow2: rev scale, exact
    float apsf = (float)(2.0 * 3.14159265358979323846 * df * 0.5);

    size_t need_ws = (size_t)B * 32;                // 2 x float4 per row
    bool flat_ok = d_ws && ws_size >= need_ws && F > 2048 &&
                   lim_f2 == half && (half & 1ull) == 0ull &&
                   half < (1ull << 31);
    if (flat_ok) {
        float4* rc = (float4*)d_ws;
        cbc_rows_kernel<<<dim3((unsigned)((B + 255) / 256)), dim3(256), 0, stream>>>(
            mass1, mass2, s1z, s2z, dist, incl, rc, (int)B, dff);
        unsigned int totalPairs = (unsigned int)(half >> 1);
        unsigned int nblk = (unsigned int)((half + 2048ull - 1ull) / 2048ull);
        cbc_flat2_main<<<dim3(nblk), dim3(256), 0, stream>>>(
            rc, (nv4*)d_out, totalPairs, (int)F, (int)B, dff, hdff);
    } else {
        dim3 grid((unsigned)((F + 256 * FB_COLS - 1) / (256 * FB_COLS)),
                  (unsigned)((B + FB_ROWS - 1) / FB_ROWS));
        cbc_fallback_kernel<<<grid, dim3(256), 0, stream>>>(
            mass1, mass2, s1z, s2z, dist, incl,
            (float2*)d_out, lim_f2, (int)B, (int)F, dff, apsf);
    }
}